// Round 1
// baseline (181.840 us; speedup 1.0000x reference)
//
#include <hip/hip_runtime.h>

// DP over (min,+) path recurrence, one wave (64 lanes) per image.
// Image: H=256 rows x W=256 cols. Lane l owns columns 4l..4l+3.
// Per row: softplus -> row prefix-sum S, A=min(v,shift(v)), prefix-min of
// (A - Sprev), V = S + prefmin. All scans via in-wave shuffles (no LDS).

#define HH 256
#define WW 256
#define NULLV 1e30f

__device__ __forceinline__ float softplus_f(float x) {
    // stable softplus: max(x,0) + log1p(exp(-|x|)), fast intrinsics
    float ax = fabsf(x);
    float t  = __expf(-ax);
    return fmaxf(x, 0.0f) + __logf(1.0f + t);
}

__global__ __launch_bounds__(64) void dp_kernel(const float* __restrict__ img,
                                                float* __restrict__ out) {
    const int b    = blockIdx.x;
    const int lane = threadIdx.x;  // 0..63

    const float4* rowp = reinterpret_cast<const float4*>(img + (size_t)b * HH * WW);
    // rowp stride per row: WW/4 = 64 float4's; lane l reads element l.

    // ---- row 0: v = cumsum(softplus(row0)) ----
    float4 cur = rowp[lane];                 // row 0
    float4 nxt = rowp[(size_t)(WW / 4) + lane];  // prefetch row 1

    float v0, v1, v2, v3;
    {
        float t0 = softplus_f(cur.x);
        float t1 = t0 + softplus_f(cur.y);
        float t2 = t1 + softplus_f(cur.z);
        float t3 = t2 + softplus_f(cur.w);
        float s = t3;
#pragma unroll
        for (int d = 1; d < 64; d <<= 1) {
            float y = __shfl_up(s, d, 64);
            s += (lane >= d) ? y : 0.0f;
        }
        float off = __shfl_up(s, 1, 64);
        off = (lane == 0) ? 0.0f : off;
        v0 = off + t0; v1 = off + t1; v2 = off + t2; v3 = off + t3;
    }

    // ---- rows 1..255 ----
    for (int r = 1; r < HH; ++r) {
        cur = nxt;
        int rn = (r + 1 < HH) ? (r + 1) : r;  // clamp tail (dummy reload)
        nxt = rowp[(size_t)rn * (WW / 4) + lane];

        float th0 = softplus_f(cur.x);
        float th1 = softplus_f(cur.y);
        float th2 = softplus_f(cur.z);
        float th3 = softplus_f(cur.w);

        // serial inclusive sums within lane
        float t0 = th0;
        float t1 = t0 + th1;
        float t2 = t1 + th2;
        float t3 = t2 + th3;

        // wave exclusive +scan of lane totals
        float s = t3;
#pragma unroll
        for (int d = 1; d < 64; d <<= 1) {
            float y = __shfl_up(s, d, 64);
            s += (lane >= d) ? y : 0.0f;
        }
        float soff = __shfl_up(s, 1, 64);
        soff = (lane == 0) ? 0.0f : soff;

        float S0 = soff + t0, S1 = soff + t1, S2 = soff + t2, S3 = soff + t3;
        float P0 = soff, P1 = S0, P2 = S1, P3 = S2;  // Sprev

        // A = min(vprev, shift_right(vprev))
        float vm1 = __shfl_up(v3, 1, 64);
        vm1 = (lane == 0) ? NULLV : vm1;
        float A0 = fminf(v0, vm1);
        float A1 = fminf(v1, v0);
        float A2 = fminf(v2, v1);
        float A3 = fminf(v3, v2);

        float B0 = A0 - P0, B1 = A1 - P1, B2 = A2 - P2, B3 = A3 - P3;

        // serial inclusive min within lane
        float m0 = B0;
        float m1 = fminf(m0, B1);
        float m2 = fminf(m1, B2);
        float m3 = fminf(m2, B3);

        // wave exclusive min-scan of lane totals
        float mm = m3;
#pragma unroll
        for (int d = 1; d < 64; d <<= 1) {
            float y = __shfl_up(mm, d, 64);
            mm = (lane >= d) ? fminf(mm, y) : mm;
        }
        float moff = __shfl_up(mm, 1, 64);
        moff = (lane == 0) ? NULLV : moff;

        v0 = S0 + fminf(moff, m0);
        v1 = S1 + fminf(moff, m1);
        v2 = S2 + fminf(moff, m2);
        v3 = S3 + fminf(moff, m3);
    }

    if (lane == 63) out[b] = v3;
}

extern "C" void kernel_launch(void* const* d_in, const int* in_sizes, int n_in,
                              void* d_out, int out_size, void* d_ws, size_t ws_size,
                              hipStream_t stream) {
    const float* img = (const float*)d_in[0];
    float* out = (float*)d_out;
    int nb = out_size;  // B = 512 images, one wave-block per image
    dp_kernel<<<nb, 64, 0, stream>>>(img, out);
}

// Round 2
// 93.210 us; speedup vs baseline: 1.9509x; 1.9509x over previous
//
#include <hip/hip_runtime.h>

// (min,+) DP, one wave (64 lanes) per image, H=W=256, lane owns 4 cols.
// All cross-lane ops via DPP (VALU-speed) instead of ds_bpermute shuffles:
//   - 64-lane inclusive scan: row_shr 1,2,4,8 + row_bcast15 + row_bcast31
//   - shift-by-one-lane: wave_shr:1
// 8 rows of float4 prefetch in flight (double-buffered groups of 4).

#define HH 256
#define WW 256
#define NULLV 1e30f

template<int CTRL, int ROWM>
__device__ __forceinline__ float dpp_mov(float x, float oldv) {
    return __builtin_bit_cast(float, __builtin_amdgcn_update_dpp(
        __builtin_bit_cast(int, oldv), __builtin_bit_cast(int, x),
        CTRL, ROWM, 0xF, false));
}

// 64-lane inclusive +scan, 6 DPP steps (rocPRIM-style gfx9 sequence)
__device__ __forceinline__ float wave_iscan_add(float x) {
    x += dpp_mov<0x111, 0xF>(x, 0.0f);  // row_shr:1
    x += dpp_mov<0x112, 0xF>(x, 0.0f);  // row_shr:2
    x += dpp_mov<0x114, 0xF>(x, 0.0f);  // row_shr:4
    x += dpp_mov<0x118, 0xF>(x, 0.0f);  // row_shr:8
    x += dpp_mov<0x142, 0xA>(x, 0.0f);  // row_bcast:15 -> rows 1,3
    x += dpp_mov<0x143, 0xC>(x, 0.0f);  // row_bcast:31 -> rows 2,3
    return x;
}

// 64-lane inclusive min-scan, identity = NULLV
__device__ __forceinline__ float wave_iscan_min(float x) {
    x = fminf(x, dpp_mov<0x111, 0xF>(x, NULLV));
    x = fminf(x, dpp_mov<0x112, 0xF>(x, NULLV));
    x = fminf(x, dpp_mov<0x114, 0xF>(x, NULLV));
    x = fminf(x, dpp_mov<0x118, 0xF>(x, NULLV));
    x = fminf(x, dpp_mov<0x142, 0xA>(x, NULLV));
    x = fminf(x, dpp_mov<0x143, 0xC>(x, NULLV));
    return x;
}

__device__ __forceinline__ float softplus_f(float x) {
    float ax = fabsf(x);
    float t  = __expf(-ax);
    return fmaxf(x, 0.0f) + __logf(1.0f + t);
}

__global__ __launch_bounds__(64) void dp_kernel(const float* __restrict__ img,
                                                float* __restrict__ out) {
    const int lane = threadIdx.x;  // 0..63
    const float4* rowp =
        reinterpret_cast<const float4*>(img + (size_t)blockIdx.x * HH * WW) + lane;
    // row r lives at rowp[r*64]

    float v0, v1, v2, v3;

    auto row0_init = [&](float4 c) {
        float t0 = softplus_f(c.x);
        float t1 = t0 + softplus_f(c.y);
        float t2 = t1 + softplus_f(c.z);
        float t3 = t2 + softplus_f(c.w);
        float s  = wave_iscan_add(t3);
        float off = dpp_mov<0x138, 0xF>(s, 0.0f);  // wave_shr:1, lane0 -> 0
        v0 = off + t0; v1 = off + t1; v2 = off + t2; v3 = off + t3;
    };

    auto row_step = [&](float4 c) {
        float th0 = softplus_f(c.x), th1 = softplus_f(c.y);
        float th2 = softplus_f(c.z), th3 = softplus_f(c.w);
        float t0 = th0, t1 = t0 + th1, t2 = t1 + th2, t3 = t2 + th3;
        float s    = wave_iscan_add(t3);
        float soff = dpp_mov<0x138, 0xF>(s, 0.0f);  // exclusive offset
        float S0 = soff + t0, S1 = soff + t1, S2 = soff + t2, S3 = soff + t3;

        float vm1 = dpp_mov<0x138, 0xF>(v3, NULLV);  // vprev shifted right 1
        float B0 = fminf(v0, vm1) - soff;
        float B1 = fminf(v1, v0) - S0;
        float B2 = fminf(v2, v1) - S1;
        float B3 = fminf(v3, v2) - S2;

        // inclusive lane-local min prefixes (tree form, depth 2)
        float m1  = fminf(B0, B1);
        float m3p = fminf(B2, B3);
        float m2  = fminf(m1, B2);
        float m3  = fminf(m1, m3p);

        float mm   = wave_iscan_min(m3);
        float moff = dpp_mov<0x138, 0xF>(mm, NULLV);  // exclusive min offset

        v0 = S0 + fminf(moff, B0);
        v1 = S1 + fminf(moff, m1);
        v2 = S2 + fminf(moff, m2);
        v3 = S3 + fminf(moff, m3);
    };

    // prologue: rows 0..7 in flight
    float4 A0 = rowp[0],   A1 = rowp[64],  A2 = rowp[128], A3 = rowp[192];
    float4 B0 = rowp[256], B1 = rowp[320], B2 = rowp[384], B3 = rowp[448];

    row0_init(A0);
    row_step(A1); row_step(A2); row_step(A3);

    const float4* p = rowp + 8 * 64;
    // 31 chunks x 8 rows: rows 4..251, with loads 4-8 rows ahead of use
    for (int c = 0; c < 31; ++c) {
        A0 = p[0];  A1 = p[64]; A2 = p[128]; A3 = p[192];   // rows 8+8c..11+8c
        row_step(B0); row_step(B1); row_step(B2); row_step(B3);
        B0 = p[256]; B1 = p[320]; B2 = p[384]; B3 = p[448]; // rows 12+8c..15+8c
        row_step(A0); row_step(A1); row_step(A2); row_step(A3);
        p += 8 * 64;
    }
    // epilogue: rows 252..255
    row_step(B0); row_step(B1); row_step(B2); row_step(B3);

    if (lane == 63) out[blockIdx.x] = v3;
}

extern "C" void kernel_launch(void* const* d_in, const int* in_sizes, int n_in,
                              void* d_out, int out_size, void* d_ws, size_t ws_size,
                              hipStream_t stream) {
    const float* img = (const float*)d_in[0];
    float* out = (float*)d_out;
    dp_kernel<<<out_size, 64, 0, stream>>>(img, out);
}

// Round 3
// 84.985 us; speedup vs baseline: 2.1397x; 1.0968x over previous
//
#include <hip/hip_runtime.h>

// (min,+) DP, one wave per image (H=W=256, lane owns 4 contiguous cols).
// Cross-lane via DPP only. Explicit 2-stage software pipeline:
//   prep(r+1)  = softplus + row prefix-sum (independent of v-chain)
//   vchain(r)  = the serial min-scan recurrence
// prep is placed before each vchain so the scheduler can fill chain stalls.
// __launch_bounds__(64,1): occupancy is grid-limited; free the VGPR budget.

#define HH 256
#define WW 256
#define NULLV 1e30f

template<int CTRL, int ROWM>
__device__ __forceinline__ float dpp_mov(float x, float oldv) {
    return __builtin_bit_cast(float, __builtin_amdgcn_update_dpp(
        __builtin_bit_cast(int, oldv), __builtin_bit_cast(int, x),
        CTRL, ROWM, 0xF, false));
}

__device__ __forceinline__ float wave_iscan_add(float x) {
    x += dpp_mov<0x111, 0xF>(x, 0.0f);  // row_shr:1
    x += dpp_mov<0x112, 0xF>(x, 0.0f);  // row_shr:2
    x += dpp_mov<0x114, 0xF>(x, 0.0f);  // row_shr:4
    x += dpp_mov<0x118, 0xF>(x, 0.0f);  // row_shr:8
    x += dpp_mov<0x142, 0xA>(x, 0.0f);  // row_bcast:15 -> rows 1,3
    x += dpp_mov<0x143, 0xC>(x, 0.0f);  // row_bcast:31 -> rows 2,3
    return x;
}

__device__ __forceinline__ float wave_iscan_min(float x) {
    x = fminf(x, dpp_mov<0x111, 0xF>(x, NULLV));
    x = fminf(x, dpp_mov<0x112, 0xF>(x, NULLV));
    x = fminf(x, dpp_mov<0x114, 0xF>(x, NULLV));
    x = fminf(x, dpp_mov<0x118, 0xF>(x, NULLV));
    x = fminf(x, dpp_mov<0x142, 0xA>(x, NULLV));
    x = fminf(x, dpp_mov<0x143, 0xC>(x, NULLV));
    return x;
}

__device__ __forceinline__ float softplus_f(float x) {
    float ax = fabsf(x);
    float t  = __expf(-ax);
    return fmaxf(x, 0.0f) + __logf(1.0f + t);
}

struct Th { float S0, S1, S2, S3, soff; };

__device__ __forceinline__ Th prep(float4 c) {
    float th0 = softplus_f(c.x), th1 = softplus_f(c.y);
    float th2 = softplus_f(c.z), th3 = softplus_f(c.w);
    float t0 = th0, t1 = t0 + th1, t2 = t1 + th2, t3 = t2 + th3;
    float s    = wave_iscan_add(t3);
    float soff = dpp_mov<0x138, 0xF>(s, 0.0f);  // wave_shr:1, lane0 -> 0
    Th t;
    t.soff = soff;
    t.S0 = soff + t0; t.S1 = soff + t1; t.S2 = soff + t2; t.S3 = soff + t3;
    return t;
}

__global__ __launch_bounds__(64, 1) void dp_kernel(const float* __restrict__ img,
                                                   float* __restrict__ out) {
    const int lane = threadIdx.x;
    const float4* rowp =
        reinterpret_cast<const float4*>(img + (size_t)blockIdx.x * HH * WW) + lane;
    // row r at rowp[r*64]

    float v0, v1, v2, v3;

    auto vchain = [&](Th t) {
        float vm1 = dpp_mov<0x138, 0xF>(v3, NULLV);  // shift right one col
        float B0 = fminf(v0, vm1) - t.soff;
        float B1 = fminf(v1, v0) - t.S0;
        float B2 = fminf(v2, v1) - t.S1;
        float B3 = fminf(v3, v2) - t.S2;
        float m1 = fminf(B0, B1);
        float m2 = fminf(m1, B2);
        float m3 = fminf(m2, B3);
        float mm   = wave_iscan_min(m3);
        float moff = dpp_mov<0x138, 0xF>(mm, NULLV);
        v0 = t.S0 + fminf(moff, B0);
        v1 = t.S1 + fminf(moff, m1);
        v2 = t.S2 + fminf(moff, m2);
        v3 = t.S3 + fminf(moff, m3);
    };

    // ---- prologue: 8 rows of loads in flight ----
    float4 LA0 = rowp[0],   LA1 = rowp[64],  LA2 = rowp[128], LA3 = rowp[192];
    float4 LB0 = rowp[256], LB1 = rowp[320], LB2 = rowp[384], LB3 = rowp[448];

    {   // row 0: v = inclusive prefix sums
        Th t0r = prep(LA0);
        v0 = t0r.S0; v1 = t0r.S1; v2 = t0r.S2; v3 = t0r.S3;
    }
    Th tC = prep(LA1);  // row 1

    const float4* p = rowp + 8 * 64;
    // 31 chunks x 8 rows: vchains for rows 1..248
    for (int c = 0; c < 31; ++c) {
        float4 NA0 = p[0], NA1 = p[64], NA2 = p[128], NA3 = p[192]; // rows 8c+8..11
        Th tN;
        tN = prep(LA2); vchain(tC);   // chain row 8c+1 | prep 8c+2
        tC = prep(LA3); vchain(tN);   // 8c+2 | 8c+3
        tN = prep(LB0); vchain(tC);   // 8c+3 | 8c+4
        tC = prep(LB1); vchain(tN);   // 8c+4 | 8c+5
        float4 NB0 = p[256], NB1 = p[320], NB2 = p[384], NB3 = p[448]; // rows 8c+12..15
        tN = prep(LB2); vchain(tC);   // 8c+5 | 8c+6
        tC = prep(LB3); vchain(tN);   // 8c+6 | 8c+7
        tN = prep(NA0); vchain(tC);   // 8c+7 | 8c+8
        tC = prep(NA1); vchain(tN);   // 8c+8 | 8c+9
        LA0 = NA0; LA1 = NA1; LA2 = NA2; LA3 = NA3;
        LB0 = NB0; LB1 = NB1; LB2 = NB2; LB3 = NB3;
        p += 8 * 64;
    }
    // ---- epilogue: rows 249..255 (state: tC=Th(249), LA=248..251, LB=252..255)
    {
        Th tN;
        tN = prep(LA2); vchain(tC);   // 249 | 250
        tC = prep(LA3); vchain(tN);   // 250 | 251
        tN = prep(LB0); vchain(tC);   // 251 | 252
        tC = prep(LB1); vchain(tN);   // 252 | 253
        tN = prep(LB2); vchain(tC);   // 253 | 254
        tC = prep(LB3); vchain(tN);   // 254 | 255
        vchain(tC);                   // 255
    }

    if (lane == 63) out[blockIdx.x] = v3;
}

extern "C" void kernel_launch(void* const* d_in, const int* in_sizes, int n_in,
                              void* d_out, int out_size, void* d_ws, size_t ws_size,
                              hipStream_t stream) {
    const float* img = (const float*)d_in[0];
    float* out = (float*)d_out;
    dp_kernel<<<out_size, 64, 0, stream>>>(img, out);
}

// Round 6
// 84.213 us; speedup vs baseline: 2.1593x; 1.0092x over previous
//
#include <hip/hip_runtime.h>

// (min,+) DP, one wave per image (H=W=256, lane owns 4 contiguous cols).
// Cross-lane via DPP. Depth-8 rolling prefetch using NORMAL loads (so the
// compiler's SIInsertWaitcnts protects every use and every RA copy) pinned
// by sched_barrier(0) fences so the loads cannot sink to their uses.
// prep(r+1) interleaved with vchain(r) inside each fence-delimited region.

#define HH 256
#define WW 256
#define NULLV 1e30f

#define SBAR() __builtin_amdgcn_sched_barrier(0)

template<int CTRL, int ROWM>
__device__ __forceinline__ float dpp_mov(float x, float oldv) {
    return __builtin_bit_cast(float, __builtin_amdgcn_update_dpp(
        __builtin_bit_cast(int, oldv), __builtin_bit_cast(int, x),
        CTRL, ROWM, 0xF, false));
}

__device__ __forceinline__ float wave_iscan_add(float x) {
    x += dpp_mov<0x111, 0xF>(x, 0.0f);  // row_shr:1
    x += dpp_mov<0x112, 0xF>(x, 0.0f);  // row_shr:2
    x += dpp_mov<0x114, 0xF>(x, 0.0f);  // row_shr:4
    x += dpp_mov<0x118, 0xF>(x, 0.0f);  // row_shr:8
    x += dpp_mov<0x142, 0xA>(x, 0.0f);  // row_bcast:15 -> rows 1,3
    x += dpp_mov<0x143, 0xC>(x, 0.0f);  // row_bcast:31 -> rows 2,3
    return x;
}

__device__ __forceinline__ float wave_iscan_min(float x) {
    x = fminf(x, dpp_mov<0x111, 0xF>(x, NULLV));
    x = fminf(x, dpp_mov<0x112, 0xF>(x, NULLV));
    x = fminf(x, dpp_mov<0x114, 0xF>(x, NULLV));
    x = fminf(x, dpp_mov<0x118, 0xF>(x, NULLV));
    x = fminf(x, dpp_mov<0x142, 0xA>(x, NULLV));
    x = fminf(x, dpp_mov<0x143, 0xC>(x, NULLV));
    return x;
}

__device__ __forceinline__ float softplus_f(float x) {
    float ax = fabsf(x);
    float t  = __expf(-ax);
    return fmaxf(x, 0.0f) + __logf(1.0f + t);
}

struct Th { float S0, S1, S2, S3, soff; };

__device__ __forceinline__ Th prep(float4 c) {
    float th0 = softplus_f(c.x), th1 = softplus_f(c.y);
    float th2 = softplus_f(c.z), th3 = softplus_f(c.w);
    float t0 = th0, t1 = t0 + th1, t2 = t1 + th2, t3 = t2 + th3;
    float s    = wave_iscan_add(t3);
    float soff = dpp_mov<0x138, 0xF>(s, 0.0f);  // wave_shr:1, lane0 -> 0
    Th t;
    t.soff = soff;
    t.S0 = soff + t0; t.S1 = soff + t1; t.S2 = soff + t2; t.S3 = soff + t3;
    return t;
}

#define ROWI(r) ((size_t)(((r) < 255) ? (r) : 255) * 64)

__global__ __launch_bounds__(64, 1) void dp_kernel(const float* __restrict__ img,
                                                   float* __restrict__ out) {
    const int lane = threadIdx.x;
    const float4* rowp =
        reinterpret_cast<const float4*>(img + (size_t)blockIdx.x * HH * WW) + lane;

    float v0, v1, v2, v3;

    auto vchain = [&](Th t) {
        float vm1 = dpp_mov<0x138, 0xF>(v3, NULLV);  // shift right one col
        float B0 = fminf(v0, vm1) - t.soff;
        float B1 = fminf(v1, v0) - t.S0;
        float B2 = fminf(v2, v1) - t.S1;
        float B3 = fminf(v3, v2) - t.S2;
        float m1 = fminf(B0, B1);
        float m2 = fminf(fminf(B0, B1), B2);   // v_min3 candidate
        float m3 = fminf(m2, B3);
        float mm   = wave_iscan_min(m3);
        float moff = dpp_mov<0x138, 0xF>(mm, NULLV);
        v0 = t.S0 + fminf(moff, B0);
        v1 = t.S1 + fminf(moff, m1);
        v2 = t.S2 + fminf(moff, m2);
        v3 = t.S3 + fminf(moff, m3);
    };

    // ---- prologue: rows 0..7 in flight ----
    float4 L0 = rowp[ROWI(0)], L1 = rowp[ROWI(1)], L2 = rowp[ROWI(2)],
           L3 = rowp[ROWI(3)], L4 = rowp[ROWI(4)], L5 = rowp[ROWI(5)],
           L6 = rowp[ROWI(6)], L7 = rowp[ROWI(7)];
    SBAR();
    {
        Th t0r = prep(L0);                 // row 0
        v0 = t0r.S0; v1 = t0r.S1; v2 = t0r.S2; v3 = t0r.S3;
    }
    L0 = rowp[ROWI(8)];
    SBAR();
    Th tC = prep(L1), tN;                  // row 1
    L1 = rowp[ROWI(9)];
    SBAR();

    // ---- 31 chunks x 8 rows: chain rows 1..248, prep one ahead,
    //      one load per step, fences keep issue 8 rows ahead of use ----
#pragma unroll 1
    for (int c = 0; c < 31; ++c) {
        const int rb = 8 * c;
        tN = prep(L2); vchain(tC); L2 = rowp[ROWI(rb + 10)]; SBAR();
        tC = prep(L3); vchain(tN); L3 = rowp[ROWI(rb + 11)]; SBAR();
        tN = prep(L4); vchain(tC); L4 = rowp[ROWI(rb + 12)]; SBAR();
        tC = prep(L5); vchain(tN); L5 = rowp[ROWI(rb + 13)]; SBAR();
        tN = prep(L6); vchain(tC); L6 = rowp[ROWI(rb + 14)]; SBAR();
        tC = prep(L7); vchain(tN); L7 = rowp[ROWI(rb + 15)]; SBAR();
        tN = prep(L0); vchain(tC); L0 = rowp[ROWI(rb + 16)]; SBAR();
        tC = prep(L1); vchain(tN); L1 = rowp[ROWI(rb + 17)]; SBAR();
    }

    // ---- epilogue: chain rows 249..255, preps from L2..L7 (rows 250..255) ----
    tN = prep(L2); vchain(tC);   // 249
    tC = prep(L3); vchain(tN);   // 250
    tN = prep(L4); vchain(tC);   // 251
    tC = prep(L5); vchain(tN);   // 252
    tN = prep(L6); vchain(tC);   // 253
    tC = prep(L7); vchain(tN);   // 254
    vchain(tC);                  // 255

    if (lane == 63) out[blockIdx.x] = v3;
}

extern "C" void kernel_launch(void* const* d_in, const int* in_sizes, int n_in,
                              void* d_out, int out_size, void* d_ws, size_t ws_size,
                              hipStream_t stream) {
    const float* img = (const float*)d_in[0];
    float* out = (float*)d_out;
    dp_kernel<<<out_size, 64, 0, stream>>>(img, out);
}